// Round 2
// baseline (214.408 us; speedup 1.0000x reference)
//
#include <hip/hip_runtime.h>
#include <hip/hip_bf16.h>
#include <hip/hip_fp16.h>

// EulerIntegrator: B=4096, D=1024, R=256, steps=8, dt=0.01
// R2: M=32 rows/block (grid 128) -> each B-fragment L2 load feeds 2 MFMAs,
// halving per-XCD L2 fragment traffic (the measured structural bottleneck:
// 32 blk/XCD * 8 steps * 1MB = 256MB @ 4.3TB/s ~ 60us of the 105us).
// sv/f kept as packed fp16 pairs to stay under the 128-VGPR cap
// (1024 thr * 4 waves/SIMD). pack_kernel rewritten: 1 coalesced float4
// read/thread, 2x threads -> fixes its latency-bound ~70us.
// GEMM1: P[32x256] = v[32x1024] @ U   (bf16 MFMA 16x16x32)
// GEMM2: G[32x1024] = (P*P)[32x256] @ W

#define BB 4096
#define DD 1024
#define RR 256
#define DT 0.01f

typedef __attribute__((ext_vector_type(8))) short short8;   // 8 bf16 = 4 VGPRs
typedef __attribute__((ext_vector_type(4))) float floatx4;  // MFMA acc

static __device__ inline unsigned short f2bf(float f) {
    union { float f; unsigned int u; } c; c.f = f;
    unsigned int u = c.u;
    u += 0x7fffu + ((u >> 16) & 1u);   // round-to-nearest-even
    return (unsigned short)(u >> 16);
}

static __device__ inline unsigned int pk2h(float a, float b) {
    unsigned int ha = __half_as_ushort(__float2half_rn(a));
    unsigned int hb = __half_as_ushort(__float2half_rn(b));
    return ha | (hb << 16);
}
static __device__ inline float lo_h(unsigned int u) {
    return __half2float(__ushort_as_half((unsigned short)(u & 0xFFFFu)));
}
static __device__ inline float hi_h(unsigned int u) {
    return __half2float(__ushort_as_half((unsigned short)(u >> 16)));
}

// Pack U [1024][256] and W [256][1024] (fp32 row-major) into bf16 MFMA
// B-fragment order: dst[(kt*NT + nt)*64 + lane] element j =
// M[kt*32 + (lane>>4)*8 + j][nt*16 + (lane&15)].
// One coalesced float4 read per thread; 4 x 2B scattered writes (tiny).
__global__ __launch_bounds__(256)
void pack_kernel(const float* __restrict__ U, const float* __restrict__ W,
                 short* __restrict__ Up, short* __restrict__ Wp) {
    int t = blockIdx.x * blockDim.x + threadIdx.x;  // 0..131071
    if (t < 65536) {
        // U: k = t>>6 (0..1023), n4 = t&63
        int k = t >> 6, n4 = t & 63;
        float4 u = *(const float4*)&U[k * RR + 4 * n4];
        int kt = k >> 5, kq = (k >> 3) & 3, j = k & 7;
        float uv[4] = {u.x, u.y, u.z, u.w};
#pragma unroll
        for (int i = 0; i < 4; i++) {
            int n = 4 * n4 + i;
            int nt = n >> 4, nl = n & 15;
            Up[(((kt * 16 + nt) * 64) + kq * 16 + nl) * 8 + j] = (short)f2bf(uv[i]);
        }
    } else {
        // W: k = 0..255, n4 = 0..255
        int t2 = t - 65536;
        int k = t2 >> 8, n4 = t2 & 255;
        float4 w = *(const float4*)&W[k * DD + 4 * n4];
        int kt = k >> 5, kq = (k >> 3) & 3, j = k & 7;
        float wv[4] = {w.x, w.y, w.z, w.w};
#pragma unroll
        for (int i = 0; i < 4; i++) {
            int n = 4 * n4 + i;
            int nt = n >> 4, nl = n & 15;
            Wp[(((kt * 64 + nt) * 64) + kq * 16 + nl) * 8 + j] = (short)f2bf(wv[i]);
        }
    }
}

__global__ __launch_bounds__(1024)
void euler_kernel(const float* __restrict__ x0,
                  const float* __restrict__ v0,
                  const float* __restrict__ force,
                  const short8* __restrict__ Up,
                  const short8* __restrict__ Wp,
                  const int* __restrict__ steps_p,
                  float* __restrict__ out) {
    // 32-row tile. v_lds padded stride 1032 shorts (16B-aligned rows).
    __shared__ __align__(16) short v_lds[32][1032];   // 66.0 KB
    __shared__ __align__(16) short p2_lds[32][264];   // 16.9 KB

    const int tid  = threadIdx.x;
    const int wave = tid >> 6;          // 0..15
    const int lane = tid & 63;
    const int nl   = lane & 15;         // M (A) / N (B) / col (C)
    const int quad = lane >> 4;         // 0..3
    const int row0 = blockIdx.x * 32;

    const int steps = steps_p[0];

    // Ownership (MFMA C/D layout of GEMM2, 2 row-groups x 4 tiles/wave):
    // element (rg, t, r): row = 16*rg + 4*quad + r, col = 64*wave + 16*t + nl
    float v_reg[2][4][4];
    unsigned int sv_pk[2][4][2];   // fp16 pairs (r = 2p, 2p+1), sum of v_t
    unsigned int f_pk[2][4][2];    // fp16 pairs, force

#pragma unroll
    for (int rg = 0; rg < 2; rg++) {
#pragma unroll
        for (int t = 0; t < 4; t++) {
            int col = 64 * wave + 16 * t + nl;
            float fv[4];
#pragma unroll
            for (int r = 0; r < 4; r++) {
                int row = 16 * rg + 4 * quad + r;
                long g = (long)(row0 + row) * DD + col;
                v_reg[rg][t][r] = v0[g];
                fv[r] = force[g];
                v_lds[row][col] = (short)f2bf(v_reg[rg][t][r]);
            }
            f_pk[rg][t][0] = pk2h(fv[0], fv[1]);
            f_pk[rg][t][1] = pk2h(fv[2], fv[3]);
            sv_pk[rg][t][0] = 0u;
            sv_pk[rg][t][1] = 0u;
        }
    }
    __syncthreads();

    for (int s = 0; s < steps; s++) {
        // ---------------- GEMM1: P = v @ U ; wave computes nt = wave, both rgs
        floatx4 acc0 = {0.f, 0.f, 0.f, 0.f};
        floatx4 acc1 = {0.f, 0.f, 0.f, 0.f};
#pragma unroll 4
        for (int kt = 0; kt < 32; kt++) {
            short8 a0 = *(const short8*)&v_lds[nl][kt * 32 + quad * 8];
            short8 a1 = *(const short8*)&v_lds[16 + nl][kt * 32 + quad * 8];
            short8 b  = Up[(kt * 16 + wave) * 64 + lane];
            acc0 = __builtin_amdgcn_mfma_f32_16x16x32_bf16(a0, b, acc0, 0, 0, 0);
            acc1 = __builtin_amdgcn_mfma_f32_16x16x32_bf16(a1, b, acc1, 0, 0, 0);
        }
        // epilogue: p^2 -> LDS (D layout: row = 16*rg + 4*quad + r, col = 16*wave + nl)
#pragma unroll
        for (int r = 0; r < 4; r++) {
            float p0 = acc0[r], p1 = acc1[r];
            p2_lds[4 * quad + r][16 * wave + nl]      = (short)f2bf(p0 * p0);
            p2_lds[16 + 4 * quad + r][16 * wave + nl] = (short)f2bf(p1 * p1);
        }
        __syncthreads();

        // ---------------- GEMM2: G = p2 @ W ; wave computes nt = 4w..4w+3, both rgs
        floatx4 acc[2][4];
#pragma unroll
        for (int rg = 0; rg < 2; rg++)
#pragma unroll
            for (int t = 0; t < 4; t++) acc[rg][t] = (floatx4){0.f, 0.f, 0.f, 0.f};
#pragma unroll 2
        for (int kt = 0; kt < 8; kt++) {
            short8 a0 = *(const short8*)&p2_lds[nl][kt * 32 + quad * 8];
            short8 a1 = *(const short8*)&p2_lds[16 + nl][kt * 32 + quad * 8];
#pragma unroll
            for (int t = 0; t < 4; t++) {
                short8 b = Wp[(kt * 64 + 4 * wave + t) * 64 + lane];
                acc[0][t] = __builtin_amdgcn_mfma_f32_16x16x32_bf16(a0, b, acc[0][t], 0, 0, 0);
                acc[1][t] = __builtin_amdgcn_mfma_f32_16x16x32_bf16(a1, b, acc[1][t], 0, 0, 0);
            }
        }
        // epilogue: Euler update, refresh bf16 v in LDS
#pragma unroll
        for (int rg = 0; rg < 2; rg++) {
#pragma unroll
            for (int t = 0; t < 4; t++) {
                int col = 64 * wave + 16 * t + nl;
                int rowb = 16 * rg + 4 * quad;
#pragma unroll
                for (int p = 0; p < 2; p++) {
                    float f0 = lo_h(f_pk[rg][t][p]), f1 = hi_h(f_pk[rg][t][p]);
                    float s0 = lo_h(sv_pk[rg][t][p]), s1 = hi_h(sv_pk[rg][t][p]);
                    float vv0 = v_reg[rg][t][2 * p];
                    float vv1 = v_reg[rg][t][2 * p + 1];
                    s0 += vv0;                       // x accumulates pre-update v
                    s1 += vv1;
                    vv0 += DT * (f0 - acc[rg][t][2 * p]);
                    vv1 += DT * (f1 - acc[rg][t][2 * p + 1]);
                    sv_pk[rg][t][p] = pk2h(s0, s1);
                    v_reg[rg][t][2 * p]     = vv0;
                    v_reg[rg][t][2 * p + 1] = vv1;
                    v_lds[rowb + 2 * p][col]     = (short)f2bf(vv0);
                    v_lds[rowb + 2 * p + 1][col] = (short)f2bf(vv1);
                }
            }
        }
        __syncthreads();
    }

    // ---------------- outputs: [cx | cv], cx = x0 + dt * sum(v_t)
    // Stage 8 rows at a time as f32 in the (now dead) v_lds, write coalesced
    // float4 lines; x0 read linearly as float4.
    float (*stage)[1032] = reinterpret_cast<float(*)[1032]>(&v_lds[0][0]);
    const float4* x4 = reinterpret_cast<const float4*>(x0);
    float4* out4 = reinterpret_cast<float4*>(out);

#pragma unroll
    for (int sel = 0; sel < 2; sel++) {          // 0: cx, 1: cv
#pragma unroll
        for (int chunk = 0; chunk < 4; chunk++) {   // rows 8*chunk .. 8*chunk+7
            const int crg = chunk >> 1;          // which row-group
            const int ch  = chunk & 1;           // which half of the row-group
            __syncthreads();
            if ((quad >> 1) == ch) {
#pragma unroll
                for (int t = 0; t < 4; t++) {
                    int col = 64 * wave + 16 * t + nl;
#pragma unroll
                    for (int r = 0; r < 4; r++) {
                        float val;
                        if (sel) {
                            val = v_reg[crg][t][r];
                        } else {
                            unsigned int u = sv_pk[crg][t][r >> 1];
                            float sva = (r & 1) ? hi_h(u) : lo_h(u);
                            val = DT * sva;
                        }
                        stage[(4 * quad + r) & 7][col] = val;
                    }
                }
            }
            __syncthreads();
            // linear copy: 8 rows x 1024 cols = 2048 float4, 2 per thread
            for (int i = tid; i < 2048; i += 1024) {
                int lrow = i >> 8;               // 256 float4 per row
                int c4 = i & 255;
                long gi = (long)(row0 + chunk * 8 + lrow) * 256 + c4;
                float4 val = *(const float4*)&stage[lrow][c4 * 4];
                if (sel == 0) {
                    float4 xv = x4[gi];
                    val.x += xv.x; val.y += xv.y; val.z += xv.z; val.w += xv.w;
                    out4[gi] = val;
                } else {
                    out4[(long)BB * 256 + gi] = val;
                }
            }
        }
    }
}

extern "C" void kernel_launch(void* const* d_in, const int* in_sizes, int n_in,
                              void* d_out, int out_size, void* d_ws, size_t ws_size,
                              hipStream_t stream) {
    const float* x     = (const float*)d_in[0];
    const float* v     = (const float*)d_in[1];
    const float* force = (const float*)d_in[2];
    const float* U     = (const float*)d_in[3];
    const float* W     = (const float*)d_in[4];
    const int*   steps = (const int*)d_in[5];

    short* Up = (short*)d_ws;                 // 32768 * 16B = 512 KB
    short* Wp = Up + 32768 * 8;               // 512 KB

    pack_kernel<<<512, 256, 0, stream>>>(U, W, Up, Wp);
    euler_kernel<<<128, 1024, 0, stream>>>(x, v, force,
                                           (const short8*)Up, (const short8*)Wp,
                                           steps, (float*)d_out);
}